// Round 3
// baseline (127.796 us; speedup 1.0000x reference)
//
#include <hip/hip_runtime.h>

#define H 512
#define W 512
#define BATCH 32
#define KS 5
#define B_CHUNK 8          // batches per block; 32/8 = 4 chunks across grid.x
#define LROW 520           // padded LDS row: [4 zero][512 data][4 zero]
#define LBUF (6 * LROW)    // 6 rows per buffer = 3120 floats

typedef const __attribute__((address_space(1))) void gv_t;
typedef __attribute__((address_space(3))) void lv_t;

// Async global->LDS, 16 B per lane. lds_dst must be wave-uniform; HW scatters
// to lds_dst + lane*16. src is the per-lane global address.
__device__ __forceinline__ void async_cp16(const float* src, float* lds_dst) {
    __builtin_amdgcn_global_load_lds((gv_t*)src, (lv_t*)lds_dst, 16, 0, 0);
}

// Issue the 12 KB f-tile (6 rows x 512 floats) for one batch into ldsbuf.
// 12 chunks of 1 KB (64 lanes x 16 B); wave w takes chunks 3w..3w+2.
// Rows outside [0,H) are skipped (their LDS rows stay zero).
__device__ __forceinline__ void prefetch_tile(const float* __restrict__ fb,
                                              float* ldsbuf,
                                              int wave, int lane, int h0) {
#pragma unroll
    for (int k = 0; k < 3; ++k) {
        const int c    = wave * 3 + k;   // 0..11
        const int r    = c >> 1;         // tile row 0..5
        const int half = c & 1;          // which 1 KB half of the row
        const int gr   = h0 - 2 + r;     // global f row
        if (gr >= 0 && gr < H) {
            const float* src = fb + gr * W + half * 256 + lane * 4;
            float* dst = ldsbuf + r * LROW + 4 + half * 256;  // wave-uniform, 16B-aligned
            async_cp16(src, dst);
        }
    }
}

// Block: 256 threads = 2 output rows x 512 cols (4 cols/thread). Loops over 8
// batches; K taps PINNED in ~100 VGPRs (asm barrier stops the compiler from
// sinking the K loads into the batch loop — R1 showed VGPR=76 => K was being
// re-read from L2 8x/chunk, ~840 MB of L2 traffic); f tiles double-buffered
// in LDS with async prefetch one batch ahead.
__global__ __launch_bounds__(256, 2) void op2d_kernel(
    const float* __restrict__ f,   // (B,H,W)
    const float* __restrict__ K,   // (5,5,H,W)
    const float* __restrict__ dt,  // (B,)
    float* __restrict__ out)       // (B,H,W)
{
    __shared__ float lds[2 * LBUF];

    const int tid  = threadIdx.x;
    const int lane = tid & 63;
    const int wave = tid >> 6;
    const int w0   = (tid & 127) * 4;          // 0..508
    const int lr   = tid >> 7;                 // 0 or 1: local output row
    const int h0   = blockIdx.y * 2;
    const int h    = h0 + lr;
    const int chunk = blockIdx.x;              // batch group 0..3

    // Zero both buffers (covers the column pads and any invalid halo rows).
#pragma unroll
    for (int i = tid; i < 2 * LBUF; i += 256) lds[i] = 0.f;

    // ---- cache 25 per-pixel kernel taps in registers (coalesced float4) ----
    float4 Kv[25];
#pragma unroll
    for (int t = 0; t < 25; ++t) {
        Kv[t] = *reinterpret_cast<const float4*>(K + (t * H + h) * W + w0);
        // Opaque register barrier: forces the load to happen HERE and the
        // value to stay live in VGPRs (compiler cannot rematerialize/sink).
        asm volatile("" : "+v"(Kv[t].x), "+v"(Kv[t].y), "+v"(Kv[t].z), "+v"(Kv[t].w));
    }

    __syncthreads();   // zeros visible to all waves before any async load lands

    const float* fb0 = f + (size_t)(chunk * B_CHUNK) * H * W;
    prefetch_tile(fb0, lds, wave, lane, h0);   // batch 0 -> buffer 0

#pragma unroll
    for (int bb = 0; bb < B_CHUNK; ++bb) {
        // __syncthreads drains vmcnt(0): the wait for batch bb's tile, which
        // has had a full compute phase in flight. Also joins waves so the
        // other buffer is safe to overwrite.
        __syncthreads();

        const int cur = bb & 1;
        if (bb + 1 < B_CHUNK) {
            prefetch_tile(fb0 + (size_t)(bb + 1) * H * W,
                          lds + (1 - cur) * LBUF, wave, lane, h0);
        }

        const int b   = chunk * B_CHUNK + bb;
        const float dtb = dt[b];
        const float* Lb = lds + cur * LBUF;

        float acc0 = 0.f, acc1 = 0.f, acc2 = 0.f, acc3 = 0.f;
        float fc0 = 0.f, fc1 = 0.f, fc2 = 0.f, fc3 = 0.f;

#pragma unroll
        for (int i = 0; i < KS; ++i) {
            const int tr = lr + i;                       // tile row for this tap row
            const float* row = Lb + tr * LROW + w0;      // padded: covers cols w0-4..w0+7
            const float4 ra = *reinterpret_cast<const float4*>(row);      // cols w0-4..w0-1
            const float4 rb = *reinterpret_cast<const float4*>(row + 4);  // cols w0  ..w0+3
            const float4 rc = *reinterpret_cast<const float4*>(row + 8);  // cols w0+4..w0+7
            const float buf[12] = { ra.x, ra.y, ra.z, ra.w,
                                    rb.x, rb.y, rb.z, rb.w,
                                    rc.x, rc.y, rc.z, rc.w };

            if (i == 2) { fc0 = rb.x; fc1 = rb.y; fc2 = rb.z; fc3 = rb.w; }

#pragma unroll
            for (int j = 0; j < KS; ++j) {
                const float4 kv = Kv[i * KS + j];
                acc0 += kv.x * buf[j + 2];
                acc1 += kv.y * buf[j + 3];
                acc2 += kv.z * buf[j + 4];
                acc3 += kv.w * buf[j + 5];
            }
        }

        float4 o;
        o.x = fmaxf(fc0 + acc0 * dtb, 0.f);
        o.y = fmaxf(fc1 + acc1 * dtb, 0.f);
        o.z = fmaxf(fc2 + acc2 * dtb, 0.f);
        o.w = fmaxf(fc3 + acc3 * dtb, 0.f);
        *reinterpret_cast<float4*>(out + ((size_t)b * H + h) * W + w0) = o;
    }
}

extern "C" void kernel_launch(void* const* d_in, const int* in_sizes, int n_in,
                              void* d_out, int out_size, void* d_ws, size_t ws_size,
                              hipStream_t stream) {
    const float* f  = (const float*)d_in[0];   // (32,512,512)
    const float* K  = (const float*)d_in[1];   // (5,5,512,512)
    const float* dt = (const float*)d_in[2];   // (32,)
    float* out = (float*)d_out;

    dim3 block(256);
    dim3 grid(BATCH / B_CHUNK, H / 2);         // (4, 256)
    op2d_kernel<<<grid, block, 0, stream>>>(f, K, dt, out);
}

// Round 5
// 125.255 us; speedup vs baseline: 1.0203x; 1.0203x over previous
//
#include <hip/hip_runtime.h>

#define H 512
#define W 512
#define BATCH 32
#define KS 5
#define B_CHUNK 4            // batches resident in LDS per block; 8 chunks
#define LROW 520             // padded LDS row: [4 zero][512 data][4 zero]
#define LTILE (6 * LROW)     // one batch's 6-row f tile = 3120 floats
#define LDS_FLOATS (B_CHUNK * LTILE)   // 12480 floats = 49.9 KB

typedef const __attribute__((address_space(1))) void gv_t;
typedef __attribute__((address_space(3))) void lv_t;
typedef float nf4 __attribute__((ext_vector_type(4)));   // native vec for nt-store

__device__ __forceinline__ void async_cp16(const float* src, float* lds_dst) {
    __builtin_amdgcn_global_load_lds((gv_t*)src, (lv_t*)lds_dst, 16, 0, 0);
}

// Block: 256 threads = 2 output rows x 512 cols (4 cols/thread), ALL 4 batches
// of one chunk resident in LDS. Tap-outer loop: each K float4 is loaded and
// consumed within one i-iteration (16 immediate uses) -> no long K live
// ranges, no remat re-reads (R1's 840 MB L2 pathology), no per-batch barriers.
__global__ __launch_bounds__(256, 3) void op2d_kernel(
    const float* __restrict__ f,   // (B,H,W)
    const float* __restrict__ K,   // (5,5,H,W)
    const float* __restrict__ dt,  // (B,)
    float* __restrict__ out)       // (B,H,W)
{
    __shared__ float lds[LDS_FLOATS];

    const int tid   = threadIdx.x;
    const int lane  = tid & 63;
    const int wave  = tid >> 6;
    const int w0    = (tid & 127) * 4;          // 0..508
    const int lr    = tid >> 7;                 // 0 or 1: local output row
    const int chunk = blockIdx.x;               // 0..7
    const int h0    = blockIdx.y * 2;
    const int h     = h0 + lr;

    // Zero LDS (covers column pads and OOB halo rows). Re-done every launch.
#pragma unroll
    for (int idx = tid; idx < LDS_FLOATS; idx += 256) lds[idx] = 0.f;
    __syncthreads();   // zeros visible before any async load lands

    // ---- stage all 4 batches' f tiles: 48 units of 1 KB; wave w = batch w ----
    {
        const int b  = wave;                               // 0..3
        const int bg = chunk * B_CHUNK + b;
        const float* fb = f + (size_t)bg * H * W;
#pragma unroll
        for (int k = 0; k < 12; ++k) {                     // 6 rows x 2 halves
            const int r    = k >> 1;
            const int half = k & 1;
            const int gr   = h0 - 2 + r;
            if (gr >= 0 && gr < H) {
                const float* src = fb + (size_t)gr * W + half * 256 + lane * 4;
                float* dst = lds + b * LTILE + r * LROW + 4 + half * 256;
                async_cp16(src, dst);
            }
        }
    }
    __syncthreads();   // drains vmcnt(0): all tiles resident

    float acc[B_CHUNK][4];
#pragma unroll
    for (int b = 0; b < B_CHUNK; ++b)
#pragma unroll
        for (int p = 0; p < 4; ++p) acc[b][p] = 0.f;

    float fc[B_CHUNK][4];   // center f values (row h, cols w0..w0+3) per batch

#pragma unroll
    for (int i = 0; i < KS; ++i) {
        // 5 K taps for this kernel row: loaded here, consumed here.
        float4 Kv[KS];
#pragma unroll
        for (int j = 0; j < KS; ++j) {
            Kv[j] = *reinterpret_cast<const float4*>(
                K + ((size_t)(i * KS + j) * H + h) * W + w0);
        }

#pragma unroll
        for (int b = 0; b < B_CHUNK; ++b) {
            const float* row = lds + b * LTILE + (lr + i) * LROW + w0;
            const float4 ra = *reinterpret_cast<const float4*>(row);      // cols w0-4..w0-1
            const float4 rb = *reinterpret_cast<const float4*>(row + 4);  // cols w0  ..w0+3
            const float4 rc = *reinterpret_cast<const float4*>(row + 8);  // cols w0+4..w0+7
            const float buf[12] = { ra.x, ra.y, ra.z, ra.w,
                                    rb.x, rb.y, rb.z, rb.w,
                                    rc.x, rc.y, rc.z, rc.w };
            if (i == 2) { fc[b][0] = rb.x; fc[b][1] = rb.y;
                          fc[b][2] = rb.z; fc[b][3] = rb.w; }
#pragma unroll
            for (int j = 0; j < KS; ++j) {
                acc[b][0] += Kv[j].x * buf[j + 2];
                acc[b][1] += Kv[j].y * buf[j + 3];
                acc[b][2] += Kv[j].z * buf[j + 4];
                acc[b][3] += Kv[j].w * buf[j + 5];
            }
        }
    }

#pragma unroll
    for (int b = 0; b < B_CHUNK; ++b) {
        const int bg = chunk * B_CHUNK + b;
        const float dtb = dt[bg];
        nf4 o;
        o.x = fmaxf(fc[b][0] + acc[b][0] * dtb, 0.f);
        o.y = fmaxf(fc[b][1] + acc[b][1] * dtb, 0.f);
        o.z = fmaxf(fc[b][2] + acc[b][2] * dtb, 0.f);
        o.w = fmaxf(fc[b][3] + acc[b][3] * dtb, 0.f);
        __builtin_nontemporal_store(o,
            reinterpret_cast<nf4*>(out + ((size_t)bg * H + h) * W + w0));
    }
}

extern "C" void kernel_launch(void* const* d_in, const int* in_sizes, int n_in,
                              void* d_out, int out_size, void* d_ws, size_t ws_size,
                              hipStream_t stream) {
    const float* f  = (const float*)d_in[0];   // (32,512,512)
    const float* K  = (const float*)d_in[1];   // (5,5,512,512)
    const float* dt = (const float*)d_in[2];   // (32,)
    float* out = (float*)d_out;

    dim3 block(256);
    // x = chunk (8): consecutive blocks share the same K tile -> L2/L3 locality.
    dim3 grid(BATCH / B_CHUNK, H / 2);         // (8, 256)
    op2d_kernel<<<grid, block, 0, stream>>>(f, K, dt, out);
}

// Round 6
// 120.653 us; speedup vs baseline: 1.0592x; 1.0381x over previous
//
#include <hip/hip_runtime.h>

#define H 512
#define W 512
#define BATCH 32
#define KS 5
#define B_CHUNK 4            // batches resident in LDS per block; 8 chunks
#define LROW 520             // padded LDS row: [4 zero][512 data][4 zero]
#define LTILE (6 * LROW)     // one batch's 6-row f tile = 3120 floats
#define LDS_FLOATS (B_CHUNK * LTILE)   // 12480 floats = 49.9 KB

typedef const __attribute__((address_space(1))) void gv_t;
typedef __attribute__((address_space(3))) void lv_t;
typedef float nf4 __attribute__((ext_vector_type(4)));   // native vec for nt-store

__device__ __forceinline__ void async_cp16(const float* src, float* lds_dst) {
    __builtin_amdgcn_global_load_lds((gv_t*)src, (lv_t*)lds_dst, 16, 0, 0);
}

// Block: 256 threads = 2 output rows x 512 cols (4 cols/thread), 4 batches
// resident in LDS. Tap-row-outer loop with DOUBLE-BUFFERED K loads: row i+1's
// 5 K float4s are in flight while row i's 80 FMAs run. Grid: x=row-pair,
// y=chunk, so the 8 blocks sharing a K row-pair have IDs 256 apart -> same
// XCD under round-robin dispatch -> K served from one L2 across chunks.
__global__ __launch_bounds__(256, 3) void op2d_kernel(
    const float* __restrict__ f,   // (B,H,W)
    const float* __restrict__ K,   // (5,5,H,W)
    const float* __restrict__ dt,  // (B,)
    float* __restrict__ out)       // (B,H,W)
{
    __shared__ float lds[LDS_FLOATS];

    const int tid   = threadIdx.x;
    const int lane  = tid & 63;
    const int wave  = tid >> 6;
    const int w0    = (tid & 127) * 4;          // 0..508
    const int lr    = tid >> 7;                 // 0 or 1: local output row
    const int h0    = blockIdx.x * 2;           // row-pair (x: same-XCD K reuse)
    const int chunk = blockIdx.y;               // 0..7
    const int h     = h0 + lr;

    // Zero LDS (covers column pads and OOB halo rows).
#pragma unroll
    for (int idx = tid; idx < LDS_FLOATS; idx += 256) lds[idx] = 0.f;
    __syncthreads();   // zeros visible before any async load lands

    // ---- stage all 4 batches' f tiles: 48 units of 1 KB; wave w = batch w ----
    {
        const int b  = wave;                               // 0..3
        const int bg = chunk * B_CHUNK + b;
        const float* fb = f + (size_t)bg * H * W;
#pragma unroll
        for (int k = 0; k < 12; ++k) {                     // 6 rows x 2 halves
            const int r    = k >> 1;
            const int half = k & 1;
            const int gr   = h0 - 2 + r;
            if (gr >= 0 && gr < H) {
                const float* src = fb + (size_t)gr * W + half * 256 + lane * 4;
                float* dst = lds + b * LTILE + r * LROW + 4 + half * 256;
                async_cp16(src, dst);
            }
        }
    }

    // K tap-row 0: issue BEFORE the barrier so its latency hides behind the
    // staging drain. Double buffer Kv[2][5] (40 VGPRs live max).
    const float* Kbase = K + (size_t)h * W + w0;
    float4 Kv[2][KS];
#pragma unroll
    for (int j = 0; j < KS; ++j)
        Kv[0][j] = *reinterpret_cast<const float4*>(Kbase + (size_t)j * (H * W));

    __syncthreads();   // drains vmcnt(0): all f tiles resident (and Kv[0] too)

    float acc[B_CHUNK][4];
#pragma unroll
    for (int b = 0; b < B_CHUNK; ++b)
#pragma unroll
        for (int p = 0; p < 4; ++p) acc[b][p] = 0.f;

    float fc[B_CHUNK][4];   // center f values (row h, cols w0..w0+3) per batch

#pragma unroll
    for (int i = 0; i < KS; ++i) {
        // Prefetch tap-row i+1 while computing with row i.
        if (i + 1 < KS) {
#pragma unroll
            for (int j = 0; j < KS; ++j)
                Kv[(i + 1) & 1][j] = *reinterpret_cast<const float4*>(
                    Kbase + (size_t)((i + 1) * KS + j) * (H * W));
        }
        const float4* Kc = Kv[i & 1];

#pragma unroll
        for (int b = 0; b < B_CHUNK; ++b) {
            const float* row = lds + b * LTILE + (lr + i) * LROW + w0;
            const float4 ra = *reinterpret_cast<const float4*>(row);      // cols w0-4..w0-1
            const float4 rb = *reinterpret_cast<const float4*>(row + 4);  // cols w0  ..w0+3
            const float4 rc = *reinterpret_cast<const float4*>(row + 8);  // cols w0+4..w0+7
            const float buf[12] = { ra.x, ra.y, ra.z, ra.w,
                                    rb.x, rb.y, rb.z, rb.w,
                                    rc.x, rc.y, rc.z, rc.w };
            if (i == 2) { fc[b][0] = rb.x; fc[b][1] = rb.y;
                          fc[b][2] = rb.z; fc[b][3] = rb.w; }
#pragma unroll
            for (int j = 0; j < KS; ++j) {
                acc[b][0] += Kc[j].x * buf[j + 2];
                acc[b][1] += Kc[j].y * buf[j + 3];
                acc[b][2] += Kc[j].z * buf[j + 4];
                acc[b][3] += Kc[j].w * buf[j + 5];
            }
        }
    }

#pragma unroll
    for (int b = 0; b < B_CHUNK; ++b) {
        const int bg = chunk * B_CHUNK + b;
        const float dtb = dt[bg];
        nf4 o;
        o.x = fmaxf(fc[b][0] + acc[b][0] * dtb, 0.f);
        o.y = fmaxf(fc[b][1] + acc[b][1] * dtb, 0.f);
        o.z = fmaxf(fc[b][2] + acc[b][2] * dtb, 0.f);
        o.w = fmaxf(fc[b][3] + acc[b][3] * dtb, 0.f);
        __builtin_nontemporal_store(o,
            reinterpret_cast<nf4*>(out + ((size_t)bg * H + h) * W + w0));
    }
}

extern "C" void kernel_launch(void* const* d_in, const int* in_sizes, int n_in,
                              void* d_out, int out_size, void* d_ws, size_t ws_size,
                              hipStream_t stream) {
    const float* f  = (const float*)d_in[0];   // (32,512,512)
    const float* K  = (const float*)d_in[1];   // (5,5,512,512)
    const float* dt = (const float*)d_in[2];   // (32,)
    float* out = (float*)d_out;

    dim3 block(256);
    // x = row-pair (256), y = chunk (8): same-K blocks are 256 IDs apart ->
    // same XCD under round-robin dispatch.
    dim3 grid(H / 2, BATCH / B_CHUNK);
    op2d_kernel<<<grid, block, 0, stream>>>(f, K, dt, out);
}